// Round 11
// baseline (297.151 us; speedup 1.0000x reference)
//
#include <hip/hip_runtime.h>
#include <math.h>

// Problem constants
#define CC 3
#define HH 1280
#define WW 720
#define BSZ 20
#define NHB 64
#define NWB 36
#define NBLK (NHB*NWB)          // 2304
#define OUT_IMG (3*5120*2880)   // 44236800

#define SLAB_PITCH 84           // 80 cols + pad; 84 % 32 = 20 -> row-bank offsets distinct
#define SLAB_ROWS  60           // 3 c * 20 out-rows per slab (5 conv rows x 4 r1 x 3 c)

// Union'd LDS: light and gate are block-uniform branches of one kernel.
union __align__(16) SMem {
  struct {
    float in_s[3][22][24];             // zero-padded input block, rows padded to 24
    float w_t[27][48];                 // transposed light weights [k][oc] (float2 per oc-pair)
    float b_s[48];
    float slab[SLAB_ROWS][SLAB_PITCH]; // pixel-shuffled output slab (WAVE-PRIVATE rows)
  } L;                                  // ~31.9 KB
  struct {
    float ins[3][26][28];              // clamped input patch (edge pad baked in)
    float w1t[27][16];                 // transposed conv1 weights [k][oc]
    float b1s[16];
    float w2t[16][9][8];               // transposed conv2 weights [ic][k][oc2]
    float b2s[8];
    float w3s[200];
    float x1s[16][12][14];             // post-pool conv1 patch, cols padded to 14
    float red[256];
    float b3s;
  } G;                                  // ~27.7 KB
};

__device__ __forceinline__ float fast_tanh(float x) {
  const float ax = fabsf(x);
  const float e = __expf(-2.0f * ax);
  const float t = (1.0f - e) / (1.0f + e);
  return x < 0.0f ? -t : t;
}

// ---------------------------------------------------------------------------
// Light expert: per 20x20 block, zero-pad conv3x3 (3->48) + pixel_shuffle(4)
// + clamp[0,0.6]+0.4. mask always False -> complex expert dead.
// r9 structure (wave-private slab, no conv barriers) + 2 oc per thread.
// Thread = (ocp, hl): oc pair (2*ocp, 2*ocp+1) shares one slab row (same
// c,r1; r2 = 2e,2e+1) -> ds_write_b64. Conv row reads amortized over 2 oc:
// b128 reads/block 864 -> 432. acc[2][20] = 40 regs (acc[4][*] proven fatal
// r2/r5; this matches the proven r0 live-set size). Conv runs on 120 threads
// (2 waves); waves 2,3 exit after staging (issue-slot cost only).
// Wave-private drain: slab row j is written by tids 2j,2j+1 -> wave 0 owns
// rows j=0..31, wave 1 owns j=32..59; 10 drain float4 per lane each.
// r8 lesson: direct global scatter stores are WORSE - keep slab drain.
// ---------------------------------------------------------------------------
__device__ __forceinline__ void light_body(
    SMem& sm, int l,
    const float* __restrict__ inp,
    const float* __restrict__ wl,
    const float* __restrict__ bl,
    float* __restrict__ out) {
  const int bi = l / NWB, bj = l % NWB;
  const int tid = threadIdx.x;

  // stage transposed weights: w_t[k][oc] = wl[oc*27 + k]
  for (int i = tid; i < 27*48; i += 256) {
    int k = i / 48, oc = i - k*48;
    sm.L.w_t[k][oc] = wl[oc*27 + k];
  }
  if (tid < 48) sm.L.b_s[tid] = bl[tid];
  for (int i = tid; i < 3*22*24; i += 256) ((float*)sm.L.in_s)[i] = 0.0f;
  __syncthreads();
  // stage 20x20x3 block; global float4 loads (WW=720 and 20*bj are mult of 4)
  for (int i = tid; i < 300; i += 256) {
    int x4 = i % 5; int r = (i / 5) % 20; int c = i / 100;
    const float4 v = *(const float4*)&inp[(c*HH + bi*BSZ + r)*WW + bj*BSZ + 4*x4];
    float* dst = &sm.L.in_s[c][r+1][1 + 4*x4];
    dst[0] = v.x; dst[1] = v.y; dst[2] = v.z; dst[3] = v.w;
  }
  __syncthreads();

  if (tid < 120) {
    const int ocp = tid % 24;            // oc pair: oc = 2*ocp + {0,1}
    const int hl  = tid / 24;            // 0..4: conv row within slab
    const int c   = ocp >> 3;            // pixel-shuffle: c  = oc>>4
    const int r1  = (ocp >> 1) & 3;      //                r1 = (oc>>2)&3
    const int e   = ocp & 1;             //                r2 = 2*e + {0,1}
    const int srow = c*20 + hl*4 + r1;   // slab row this thread writes

    // wave-private drain geometry: slab row j = hl*12 + c*4 + r1 is written
    // by tids 2j, 2j+1; wave 0 = rows 0..31, wave 1 = rows 32..59
    const int wv    = tid >> 6;                  // 0 or 1
    const int lane  = tid & 63;                  // wave1 active: 0..55
    const int nlane = wv ? 56 : 64;
    const int nf4   = wv ? 560 : 640;            // own_rows * 20 float4
    const int j0    = wv ? 32 : 0;
    const int row0 = bi * 80, col0 = bj * 80;

    #pragma unroll 1
    for (int slab = 0; slab < 4; ++slab) {
      const int h = slab*5 + hl;
      float acc0[20], acc1[20];
      {
        const float2 b2 = *(const float2*)&sm.L.b_s[2*ocp];
        #pragma unroll
        for (int w = 0; w < 20; ++w) { acc0[w] = b2.x; acc1[w] = b2.y; }
      }

      #pragma unroll
      for (int ic = 0; ic < 3; ++ic)
        #pragma unroll
        for (int ky = 0; ky < 3; ++ky) {
          const float* row = &sm.L.in_s[ic][h + ky][0];
          float r[24];
          #pragma unroll
          for (int jj = 0; jj < 6; ++jj) {
            float4 v = ((const float4*)row)[jj];   // ds_read_b128, ~3 addrs/wave
            r[jj*4+0] = v.x; r[jj*4+1] = v.y; r[jj*4+2] = v.z; r[jj*4+3] = v.w;
          }
          const int kbase = (ic*3 + ky)*3;
          const float2 w0 = *(const float2*)&sm.L.w_t[kbase + 0][2*ocp];
          const float2 w1 = *(const float2*)&sm.L.w_t[kbase + 1][2*ocp];
          const float2 w2 = *(const float2*)&sm.L.w_t[kbase + 2][2*ocp];
          #pragma unroll
          for (int w = 0; w < 20; ++w) {
            acc0[w] += r[w]*w0.x + r[w+1]*w1.x + r[w+2]*w2.x;
            acc1[w] += r[w]*w0.y + r[w+1]*w1.y + r[w+2]*w2.y;
          }
        }

      // pixel_shuffle scatter -> wave-private slab row, float2 (r2 = 2e,2e+1)
      float* dst = &sm.L.slab[srow][2*e];
      #pragma unroll
      for (int w = 0; w < 20; ++w) {
        float2 v;
        v.x = fminf(fmaxf(acc0[w], 0.0f), 0.6f) + 0.4f;
        v.y = fminf(fmaxf(acc1[w], 0.0f), 0.6f) + 0.4f;
        *(float2*)&dst[4*w] = v;
      }

      // wave-local drain of this wave's own rows (no __syncthreads: rows are
      // wave-private; DS ops are in-order per wave — r9-validated pattern)
      #pragma unroll 1
      for (int q = lane; q < nf4; q += nlane) {
        const int rloc = q / 20, cb = q % 20;
        const int j    = j0 + rloc;
        const int hl_j = j / 12;
        const int rem  = j - hl_j*12;
        const int c_j  = rem >> 2;
        const int r1_j = rem & 3;
        const float4 v = *(const float4*)&sm.L.slab[c_j*20 + hl_j*4 + r1_j][4*cb];
        const int gy = row0 + slab*20 + hl_j*4 + r1_j;
        *(float4*)&out[(c_j*5120 + gy)*2880 + col0 + 4*cb] = v;
      }
    }
  }
}

// ---------------------------------------------------------------------------
// Fused gate CNN (round-7 version, UNTOUCHED - proven: conflicts halved):
//   stage A: 4 oc per patch load (patch LDS reads /4, float2 reads, float4 w)
//   stage B: 4 oc2 per window (window LDS reads /4, float4 broadcast weights)
//   stage C: reduce 200 products + sigmoid
// ---------------------------------------------------------------------------
__device__ __forceinline__ void gate_body(
    SMem& sm, int l,
    const float* __restrict__ inp,
    const float* __restrict__ w1,
    const float* __restrict__ b1,
    const float* __restrict__ w2,
    const float* __restrict__ b2,
    const float* __restrict__ w3,
    const float* __restrict__ b3,
    float* __restrict__ cv) {
  const int tid = threadIdx.x;
  const int oy = l / NWB, ox = l % NWB;

  // transposed conv1 weights: w1t[k][oc] = w1[oc*27 + k]
  for (int i = tid; i < 27*16; i += 256) {
    int k = i >> 4, oc = i & 15;
    sm.G.w1t[k][oc] = w1[oc*27 + k];
  }
  // transposed conv2 weights: w2t[ic][k][oc2] = w2[(oc2*16+ic)*9 + k]
  for (int i = tid; i < 16*9*8; i += 256) {
    int ic = i / 72; int rem = i - ic*72; int k = rem >> 3; int oc2 = rem & 7;
    ((float*)sm.G.w2t)[i] = w2[(oc2*16 + ic)*9 + k];
  }
  for (int i = tid; i < 200; i += 256) sm.G.w3s[i] = w3[i];
  if (tid < 16) sm.G.b1s[tid] = b1[tid];
  if (tid < 8)  sm.G.b2s[tid] = b2[tid];
  if (tid == 0) sm.G.b3s = b3[0];

  // input patch rows [20*oy-3, 20*oy+23), cols [20*ox-3, 20*ox+23), clamped
  for (int i = tid; i < 3*26*28; i += 256) {
    int b = i % 28; int a = (i / 28) % 26; int ic = i / (26*28);
    int gy = 20*oy - 3 + a; gy = gy < 0 ? 0 : (gy > HH-1 ? HH-1 : gy);
    int gx = 20*ox - 3 + b; gx = gx < 0 ? 0 : (gx > WW-1 ? WW-1 : gx);
    sm.G.ins[ic][a][b] = inp[(ic*HH + gy)*WW + gx];
  }
  __syncthreads();

  // ---- stage A: 4 oc per thread-iteration, patch loaded once per 4 oc
  for (int idx = tid; idx < 4*144; idx += 256) {
    const int ocq = idx / 144;                 // 0..3 -> oc = 4*ocq + q
    const int pos = idx - ocq*144;
    const int ly = pos / 12, lx = pos - ly*12;
    int y1 = 10*oy - 1 + ly; y1 = y1 < 0 ? 0 : (y1 > 639 ? 639 : y1);
    int x1 = 10*ox - 1 + lx; x1 = x1 < 0 ? 0 : (x1 > 359 ? 359 : x1);
    const int ry = 2*y1 + 2 - 20*oy;           // even, in [0,22]
    const int rx = 2*x1 + 2 - 20*ox;           // even, in [0,24]

    float patch[3][4][4];
    #pragma unroll
    for (int ic = 0; ic < 3; ++ic)
      #pragma unroll
      for (int d = 0; d < 4; ++d) {
        const float2 pa = *(const float2*)&sm.G.ins[ic][ry + d][rx];
        const float2 pb = *(const float2*)&sm.G.ins[ic][ry + d][rx + 2];
        patch[ic][d][0] = pa.x; patch[ic][d][1] = pa.y;
        patch[ic][d][2] = pb.x; patch[ic][d][3] = pb.y;
      }

    const float4 b4 = *(const float4*)&sm.G.b1s[4*ocq];
    float a00[4], a01[4], a10[4], a11[4];
    a00[0]=b4.x; a00[1]=b4.y; a00[2]=b4.z; a00[3]=b4.w;
    a01[0]=b4.x; a01[1]=b4.y; a01[2]=b4.z; a01[3]=b4.w;
    a10[0]=b4.x; a10[1]=b4.y; a10[2]=b4.z; a10[3]=b4.w;
    a11[0]=b4.x; a11[1]=b4.y; a11[2]=b4.z; a11[3]=b4.w;

    #pragma unroll
    for (int ic = 0; ic < 3; ++ic)
      #pragma unroll
      for (int ky = 0; ky < 3; ++ky)
        #pragma unroll
        for (int kx = 0; kx < 3; ++kx) {
          const int k = (ic*3 + ky)*3 + kx;
          const float4 wv = *(const float4*)&sm.G.w1t[k][4*ocq];
          const float p00 = patch[ic][ky  ][kx  ];
          const float p01 = patch[ic][ky  ][kx+1];
          const float p10 = patch[ic][ky+1][kx  ];
          const float p11 = patch[ic][ky+1][kx+1];
          a00[0] += p00*wv.x; a00[1] += p00*wv.y; a00[2] += p00*wv.z; a00[3] += p00*wv.w;
          a01[0] += p01*wv.x; a01[1] += p01*wv.y; a01[2] += p01*wv.z; a01[3] += p01*wv.w;
          a10[0] += p10*wv.x; a10[1] += p10*wv.y; a10[2] += p10*wv.z; a10[3] += p10*wv.w;
          a11[0] += p11*wv.x; a11[1] += p11*wv.y; a11[2] += p11*wv.z; a11[3] += p11*wv.w;
        }

    #pragma unroll
    for (int q = 0; q < 4; ++q) {
      const float m = fmaxf(fmaxf(a00[q], a01[q]), fmaxf(a10[q], a11[q]));
      // tanh monotonic: maxpool(tanh(.)) == tanh(maxpool(.))
      sm.G.x1s[4*ocq + q][ly][lx] = fast_tanh(m);
    }
  }
  __syncthreads();

  // ---- stage B: 4 oc2 per thread; x1s window read once per oc2-quad.
  sm.G.red[tid] = 0.0f;
  __syncthreads();
  if (tid < 50) {
    const int q   = tid / 25;
    const int win = tid - q*25;
    const int j = win / 5, i5 = win - j*5;

    const float4 b4 = *(const float4*)&sm.G.b2s[4*q];
    float a00[4], a01[4], a10[4], a11[4];
    a00[0]=b4.x; a00[1]=b4.y; a00[2]=b4.z; a00[3]=b4.w;
    a01[0]=b4.x; a01[1]=b4.y; a01[2]=b4.z; a01[3]=b4.w;
    a10[0]=b4.x; a10[1]=b4.y; a10[2]=b4.z; a10[3]=b4.w;
    a11[0]=b4.x; a11[1]=b4.y; a11[2]=b4.z; a11[3]=b4.w;

    for (int ic = 0; ic < 16; ++ic) {
      float p[4][4];
      #pragma unroll
      for (int d = 0; d < 4; ++d) {
        const float2 pa = *(const float2*)&sm.G.x1s[ic][2*j + d][2*i5];
        const float2 pb = *(const float2*)&sm.G.x1s[ic][2*j + d][2*i5 + 2];
        p[d][0] = pa.x; p[d][1] = pa.y; p[d][2] = pb.x; p[d][3] = pb.y;
      }
      #pragma unroll
      for (int ky = 0; ky < 3; ++ky)
        #pragma unroll
        for (int kx = 0; kx < 3; ++kx) {
          const float4 wv = *(const float4*)&sm.G.w2t[ic][ky*3 + kx][4*q];
          const float p00 = p[ky  ][kx  ];
          const float p01 = p[ky  ][kx+1];
          const float p10 = p[ky+1][kx  ];
          const float p11 = p[ky+1][kx+1];
          a00[0] += p00*wv.x; a00[1] += p00*wv.y; a00[2] += p00*wv.z; a00[3] += p00*wv.w;
          a01[0] += p01*wv.x; a01[1] += p01*wv.y; a01[2] += p01*wv.z; a01[3] += p01*wv.w;
          a10[0] += p10*wv.x; a10[1] += p10*wv.y; a10[2] += p10*wv.z; a10[3] += p10*wv.w;
          a11[0] += p11*wv.x; a11[1] += p11*wv.y; a11[2] += p11*wv.z; a11[3] += p11*wv.w;
        }
    }
    #pragma unroll
    for (int qq = 0; qq < 4; ++qq) {
      const float x2 = fmaxf(fmaxf(a00[qq], a01[qq]), fmaxf(a10[qq], a11[qq]));
      const int o2 = 4*q + qq;
      sm.G.red[o2*25 + win] = x2 * sm.G.w3s[o2*25 + win];
    }
  }
  __syncthreads();

  // ---- stage C
  if (tid < 64) {
    float s = sm.G.red[tid] + sm.G.red[tid+64] + sm.G.red[tid+128] + sm.G.red[tid+192];
    #pragma unroll
    for (int off = 32; off > 0; off >>= 1) s += __shfl_down(s, off);
    if (tid == 0)
      cv[l] = 1.0f / (1.0f + expf(-(s + sm.G.b3s)));
  }
}

// ---------------------------------------------------------------------------
// One launch, interleaved light/gate blocks (block-uniform branch).
// ---------------------------------------------------------------------------
__global__ __launch_bounds__(256) void fused_kernel(
    const float* __restrict__ inp,
    const float* __restrict__ w1,
    const float* __restrict__ b1,
    const float* __restrict__ w2,
    const float* __restrict__ b2,
    const float* __restrict__ w3,
    const float* __restrict__ b3,
    const float* __restrict__ wl,
    const float* __restrict__ bl,
    float* __restrict__ out) {
  __shared__ SMem sm;
  const int bid = blockIdx.x;
  if (bid & 1)
    gate_body(sm, bid >> 1, inp, w1, b1, w2, b2, w3, b3, out + OUT_IMG);
  else
    light_body(sm, bid >> 1, inp, wl, bl, out);
}

// ---------------------------------------------------------------------------
extern "C" void kernel_launch(void* const* d_in, const int* in_sizes, int n_in,
                              void* d_out, int out_size, void* d_ws, size_t ws_size,
                              hipStream_t stream) {
  const float* inp = (const float*)d_in[0];
  const float* w1  = (const float*)d_in[1];
  const float* b1  = (const float*)d_in[2];
  const float* w2  = (const float*)d_in[3];
  const float* b2  = (const float*)d_in[4];
  const float* w3  = (const float*)d_in[5];
  const float* b3  = (const float*)d_in[6];
  const float* wl  = (const float*)d_in[7];
  const float* bl  = (const float*)d_in[8];
  // d_in[9..14] = wc1,bc1,wc2,bc2,wc3,bc3: dead (gate sigmoid <= 1 -> mask always False)

  float* out = (float*)d_out;

  hipLaunchKernelGGL(fused_kernel, dim3(2*NBLK), dim3(256), 0, stream,
                     inp, w1, b1, w2, b2, w3, b3, wl, bl, out);
}

// Round 12
// 257.321 us; speedup vs baseline: 1.1548x; 1.1548x over previous
//
#include <hip/hip_runtime.h>
#include <math.h>

// Problem constants
#define CC 3
#define HH 1280
#define WW 720
#define BSZ 20
#define NHB 64
#define NWB 36
#define NBLK (NHB*NWB)          // 2304
#define OUT_IMG (3*5120*2880)   // 44236800

#define SLAB_PITCH 84           // 80 cols + pad; 84 % 32 = 20 -> row-bank offsets distinct
#define SLAB_ROWS  60           // 3 c * 20 out-rows per slab (5 conv rows x 4 r1 x 3 c)

// Union'd LDS: light and gate are block-uniform branches of one kernel.
// This is the r9 configuration — best measured (~107us kernel, 257.3us total).
// r8 lesson: no-slab direct scatter stores = 130us (VMEM backpressure).
// r11 lesson: 2-oc/thread (120-thread conv) = 145us (TLP collapse, occ 27%).
// r2-r5 lesson: any per-thread footprint widening loses to the allocator.
// => kernel is latency/TLP-bound; keep 240 working threads + slab drain.
union __align__(16) SMem {
  struct {
    float in_s[3][22][24];             // zero-padded input block, rows padded to 24
    float w_s[48*27 + 48];
    float slab[SLAB_ROWS][SLAB_PITCH]; // pixel-shuffled output slab (WAVE-PRIVATE rows)
  } L;                                  // ~31.9 KB
  struct {
    float ins[3][26][28];              // clamped input patch (edge pad baked in)
    float w1t[27][16];                 // transposed conv1 weights [k][oc]
    float b1s[16];
    float w2t[16][9][8];               // transposed conv2 weights [ic][k][oc2]
    float b2s[8];
    float w3s[200];
    float x1s[16][12][14];             // post-pool conv1 patch, cols padded to 14
    float red[256];
    float b3s;
  } G;                                  // ~27.7 KB
};

__device__ __forceinline__ float fast_tanh(float x) {
  const float ax = fabsf(x);
  const float e = __expf(-2.0f * ax);
  const float t = (1.0f - e) / (1.0f + e);
  return x < 0.0f ? -t : t;
}

// ---------------------------------------------------------------------------
// Light expert: per 20x20 block, zero-pad conv3x3 (3->48) + pixel_shuffle(4)
// + clamp[0,0.6]+0.4. mask always False -> complex expert dead.
// Thread = one (oc,hl) with acc[20] (the PROVEN 48-VGPR conv structure).
// Wave-private slab: each pixel-shuffle quad (4 lanes, r2=0..3 of one slab
// row) is 4 consecutive lanes starting at a multiple of 4, never straddling
// a 64-lane boundary -> every slab row is written by exactly one wave. Each
// wave drains its OWN 16 rows right after writing (in-wave DS ordering via
// lgkmcnt; no __syncthreads). 2 barriers total.
// ---------------------------------------------------------------------------
__device__ __forceinline__ void light_body(
    SMem& sm, int l,
    const float* __restrict__ inp,
    const float* __restrict__ wl,
    const float* __restrict__ bl,
    float* __restrict__ out) {
  const int bi = l / NWB, bj = l % NWB;
  const int tid = threadIdx.x;
  float* w_s = sm.L.w_s;

  for (int i = tid; i < 3*22*24; i += 256) ((float*)sm.L.in_s)[i] = 0.0f;
  for (int i = tid; i < 48*27; i += 256) w_s[i] = wl[i];
  if (tid < 48) w_s[48*27 + tid] = bl[tid];
  __syncthreads();
  // stage 20x20x3 block; global float4 loads (WW=720 and 20*bj are mult of 4)
  for (int i = tid; i < 300; i += 256) {
    int x4 = i % 5; int r = (i / 5) % 20; int c = i / 100;
    const float4 v = *(const float4*)&inp[(c*HH + bi*BSZ + r)*WW + bj*BSZ + 4*x4];
    float* dst = &sm.L.in_s[c][r+1][1 + 4*x4];
    dst[0] = v.x; dst[1] = v.y; dst[2] = v.z; dst[3] = v.w;
  }
  __syncthreads();

  if (tid < 240) {
    const int oc = tid % 48;
    const int hl = tid / 48;            // 0..4: conv row within slab
    const int c  = oc >> 4;             // pixel-shuffle: c  = oc>>4
    const int r1 = (oc >> 2) & 3;       //                r1 = (oc>>2)&3
    const int r2 = oc & 3;              //                r2 = oc&3

    // hoisted weights (slab-invariant)
    float wr[27];
    #pragma unroll
    for (int j = 0; j < 27; ++j) wr[j] = w_s[oc*27 + j];
    const float bias = w_s[48*27 + oc];

    // wave-private drain geometry: wave wv owns quads j = 16*wv + rloc
    const int wv    = tid >> 6;                  // 0..3
    const int lane  = tid & 63;
    const int nlane = (wv == 3) ? 48 : 64;       // wave 3 has lanes 192..239
    const int nf4   = (wv == 3) ? 240 : 320;     // own_rows * 20 float4s
    const int row0 = bi * 80, col0 = bj * 80;

    #pragma unroll 1
    for (int slab = 0; slab < 4; ++slab) {
      const int h = slab*5 + hl;
      float acc[20];
      #pragma unroll
      for (int w = 0; w < 20; ++w) acc[w] = bias;

      #pragma unroll
      for (int ic = 0; ic < 3; ++ic)
        #pragma unroll
        for (int ky = 0; ky < 3; ++ky) {
          const float* row = &sm.L.in_s[ic][h + ky][0];
          float r[24];
          #pragma unroll
          for (int j = 0; j < 6; ++j) {
            float4 v = ((const float4*)row)[j];   // ds_read_b128, 2 addrs/wave
            r[j*4+0] = v.x; r[j*4+1] = v.y; r[j*4+2] = v.z; r[j*4+3] = v.w;
          }
          const float w0 = wr[ic*9 + ky*3 + 0];
          const float w1 = wr[ic*9 + ky*3 + 1];
          const float w2 = wr[ic*9 + ky*3 + 2];
          #pragma unroll
          for (int w = 0; w < 20; ++w)
            acc[w] += r[w]*w0 + r[w+1]*w1 + r[w+2]*w2;
        }

      // pixel_shuffle scatter -> wave-private slab row
      float* dst = &sm.L.slab[c*20 + hl*4 + r1][r2];
      #pragma unroll
      for (int w = 0; w < 20; ++w)
        dst[4*w] = fminf(fmaxf(acc[w], 0.0f), 0.6f) + 0.4f;

      // wave-local drain of this wave's own rows (no __syncthreads needed:
      // rows written only by this wave; lgkmcnt orders write->read in-wave)
      #pragma unroll 1
      for (int q = lane; q < nf4; q += nlane) {
        const int rloc = q / 20, cb = q % 20;
        const int j    = 16*wv + rloc;           // quad id -> (hl_j, c_j, r1_j)
        const int hl_j = j / 12;
        const int rem  = j - hl_j*12;
        const int c_j  = rem >> 2;
        const int r1_j = rem & 3;
        const float4 v = *(const float4*)&sm.L.slab[(c_j*20 + hl_j*4 + r1_j)][4*cb];
        const int gy = row0 + slab*20 + hl_j*4 + r1_j;
        *(float4*)&out[(c_j*5120 + gy)*2880 + col0 + 4*cb] = v;
      }
      // next slab's writes to the same rows are ordered after these reads
      // within the wave (program order); other waves never touch them.
    }
  }
}

// ---------------------------------------------------------------------------
// Fused gate CNN (round-7 version, proven: conflicts halved vs r1):
//   stage A: 4 oc per patch load (patch LDS reads /4, float2 reads, float4 w)
//   stage B: 4 oc2 per window (window LDS reads /4, float4 broadcast weights)
//   stage C: reduce 200 products + sigmoid
// ---------------------------------------------------------------------------
__device__ __forceinline__ void gate_body(
    SMem& sm, int l,
    const float* __restrict__ inp,
    const float* __restrict__ w1,
    const float* __restrict__ b1,
    const float* __restrict__ w2,
    const float* __restrict__ b2,
    const float* __restrict__ w3,
    const float* __restrict__ b3,
    float* __restrict__ cv) {
  const int tid = threadIdx.x;
  const int oy = l / NWB, ox = l % NWB;

  // transposed conv1 weights: w1t[k][oc] = w1[oc*27 + k]
  for (int i = tid; i < 27*16; i += 256) {
    int k = i >> 4, oc = i & 15;
    sm.G.w1t[k][oc] = w1[oc*27 + k];
  }
  // transposed conv2 weights: w2t[ic][k][oc2] = w2[(oc2*16+ic)*9 + k]
  for (int i = tid; i < 16*9*8; i += 256) {
    int ic = i / 72; int rem = i - ic*72; int k = rem >> 3; int oc2 = rem & 7;
    ((float*)sm.G.w2t)[i] = w2[(oc2*16 + ic)*9 + k];
  }
  for (int i = tid; i < 200; i += 256) sm.G.w3s[i] = w3[i];
  if (tid < 16) sm.G.b1s[tid] = b1[tid];
  if (tid < 8)  sm.G.b2s[tid] = b2[tid];
  if (tid == 0) sm.G.b3s = b3[0];

  // input patch rows [20*oy-3, 20*oy+23), cols [20*ox-3, 20*ox+23), clamped
  for (int i = tid; i < 3*26*28; i += 256) {
    int b = i % 28; int a = (i / 28) % 26; int ic = i / (26*28);
    int gy = 20*oy - 3 + a; gy = gy < 0 ? 0 : (gy > HH-1 ? HH-1 : gy);
    int gx = 20*ox - 3 + b; gx = gx < 0 ? 0 : (gx > WW-1 ? WW-1 : gx);
    sm.G.ins[ic][a][b] = inp[(ic*HH + gy)*WW + gx];
  }
  __syncthreads();

  // ---- stage A: 4 oc per thread-iteration, patch loaded once per 4 oc
  for (int idx = tid; idx < 4*144; idx += 256) {
    const int ocq = idx / 144;                 // 0..3 -> oc = 4*ocq + q
    const int pos = idx - ocq*144;
    const int ly = pos / 12, lx = pos - ly*12;
    int y1 = 10*oy - 1 + ly; y1 = y1 < 0 ? 0 : (y1 > 639 ? 639 : y1);
    int x1 = 10*ox - 1 + lx; x1 = x1 < 0 ? 0 : (x1 > 359 ? 359 : x1);
    const int ry = 2*y1 + 2 - 20*oy;           // even, in [0,22]
    const int rx = 2*x1 + 2 - 20*ox;           // even, in [0,24]

    float patch[3][4][4];
    #pragma unroll
    for (int ic = 0; ic < 3; ++ic)
      #pragma unroll
      for (int d = 0; d < 4; ++d) {
        const float2 pa = *(const float2*)&sm.G.ins[ic][ry + d][rx];
        const float2 pb = *(const float2*)&sm.G.ins[ic][ry + d][rx + 2];
        patch[ic][d][0] = pa.x; patch[ic][d][1] = pa.y;
        patch[ic][d][2] = pb.x; patch[ic][d][3] = pb.y;
      }

    const float4 b4 = *(const float4*)&sm.G.b1s[4*ocq];
    float a00[4], a01[4], a10[4], a11[4];
    a00[0]=b4.x; a00[1]=b4.y; a00[2]=b4.z; a00[3]=b4.w;
    a01[0]=b4.x; a01[1]=b4.y; a01[2]=b4.z; a01[3]=b4.w;
    a10[0]=b4.x; a10[1]=b4.y; a10[2]=b4.z; a10[3]=b4.w;
    a11[0]=b4.x; a11[1]=b4.y; a11[2]=b4.z; a11[3]=b4.w;

    #pragma unroll
    for (int ic = 0; ic < 3; ++ic)
      #pragma unroll
      for (int ky = 0; ky < 3; ++ky)
        #pragma unroll
        for (int kx = 0; kx < 3; ++kx) {
          const int k = (ic*3 + ky)*3 + kx;
          const float4 wv = *(const float4*)&sm.G.w1t[k][4*ocq];
          const float p00 = patch[ic][ky  ][kx  ];
          const float p01 = patch[ic][ky  ][kx+1];
          const float p10 = patch[ic][ky+1][kx  ];
          const float p11 = patch[ic][ky+1][kx+1];
          a00[0] += p00*wv.x; a00[1] += p00*wv.y; a00[2] += p00*wv.z; a00[3] += p00*wv.w;
          a01[0] += p01*wv.x; a01[1] += p01*wv.y; a01[2] += p01*wv.z; a01[3] += p01*wv.w;
          a10[0] += p10*wv.x; a10[1] += p10*wv.y; a10[2] += p10*wv.z; a10[3] += p10*wv.w;
          a11[0] += p11*wv.x; a11[1] += p11*wv.y; a11[2] += p11*wv.z; a11[3] += p11*wv.w;
        }

    #pragma unroll
    for (int q = 0; q < 4; ++q) {
      const float m = fmaxf(fmaxf(a00[q], a01[q]), fmaxf(a10[q], a11[q]));
      // tanh monotonic: maxpool(tanh(.)) == tanh(maxpool(.))
      sm.G.x1s[4*ocq + q][ly][lx] = fast_tanh(m);
    }
  }
  __syncthreads();

  // ---- stage B: 4 oc2 per thread; x1s window read once per oc2-quad.
  sm.G.red[tid] = 0.0f;
  __syncthreads();
  if (tid < 50) {
    const int q   = tid / 25;
    const int win = tid - q*25;
    const int j = win / 5, i5 = win - j*5;

    const float4 b4 = *(const float4*)&sm.G.b2s[4*q];
    float a00[4], a01[4], a10[4], a11[4];
    a00[0]=b4.x; a00[1]=b4.y; a00[2]=b4.z; a00[3]=b4.w;
    a01[0]=b4.x; a01[1]=b4.y; a01[2]=b4.z; a01[3]=b4.w;
    a10[0]=b4.x; a10[1]=b4.y; a10[2]=b4.z; a10[3]=b4.w;
    a11[0]=b4.x; a11[1]=b4.y; a11[2]=b4.z; a11[3]=b4.w;

    for (int ic = 0; ic < 16; ++ic) {
      float p[4][4];
      #pragma unroll
      for (int d = 0; d < 4; ++d) {
        const float2 pa = *(const float2*)&sm.G.x1s[ic][2*j + d][2*i5];
        const float2 pb = *(const float2*)&sm.G.x1s[ic][2*j + d][2*i5 + 2];
        p[d][0] = pa.x; p[d][1] = pa.y; p[d][2] = pb.x; p[d][3] = pb.y;
      }
      #pragma unroll
      for (int ky = 0; ky < 3; ++ky)
        #pragma unroll
        for (int kx = 0; kx < 3; ++kx) {
          const float4 wv = *(const float4*)&sm.G.w2t[ic][ky*3 + kx][4*q];
          const float p00 = p[ky  ][kx  ];
          const float p01 = p[ky  ][kx+1];
          const float p10 = p[ky+1][kx  ];
          const float p11 = p[ky+1][kx+1];
          a00[0] += p00*wv.x; a00[1] += p00*wv.y; a00[2] += p00*wv.z; a00[3] += p00*wv.w;
          a01[0] += p01*wv.x; a01[1] += p01*wv.y; a01[2] += p01*wv.z; a01[3] += p01*wv.w;
          a10[0] += p10*wv.x; a10[1] += p10*wv.y; a10[2] += p10*wv.z; a10[3] += p10*wv.w;
          a11[0] += p11*wv.x; a11[1] += p11*wv.y; a11[2] += p11*wv.z; a11[3] += p11*wv.w;
        }
    }
    #pragma unroll
    for (int qq = 0; qq < 4; ++qq) {
      const float x2 = fmaxf(fmaxf(a00[qq], a01[qq]), fmaxf(a10[qq], a11[qq]));
      const int o2 = 4*q + qq;
      sm.G.red[o2*25 + win] = x2 * sm.G.w3s[o2*25 + win];
    }
  }
  __syncthreads();

  // ---- stage C
  if (tid < 64) {
    float s = sm.G.red[tid] + sm.G.red[tid+64] + sm.G.red[tid+128] + sm.G.red[tid+192];
    #pragma unroll
    for (int off = 32; off > 0; off >>= 1) s += __shfl_down(s, off);
    if (tid == 0)
      cv[l] = 1.0f / (1.0f + expf(-(s + sm.G.b3s)));
  }
}

// ---------------------------------------------------------------------------
// One launch, interleaved light/gate blocks (block-uniform branch).
// ---------------------------------------------------------------------------
__global__ __launch_bounds__(256) void fused_kernel(
    const float* __restrict__ inp,
    const float* __restrict__ w1,
    const float* __restrict__ b1,
    const float* __restrict__ w2,
    const float* __restrict__ b2,
    const float* __restrict__ w3,
    const float* __restrict__ b3,
    const float* __restrict__ wl,
    const float* __restrict__ bl,
    float* __restrict__ out) {
  __shared__ SMem sm;
  const int bid = blockIdx.x;
  if (bid & 1)
    gate_body(sm, bid >> 1, inp, w1, b1, w2, b2, w3, b3, out + OUT_IMG);
  else
    light_body(sm, bid >> 1, inp, wl, bl, out);
}

// ---------------------------------------------------------------------------
extern "C" void kernel_launch(void* const* d_in, const int* in_sizes, int n_in,
                              void* d_out, int out_size, void* d_ws, size_t ws_size,
                              hipStream_t stream) {
  const float* inp = (const float*)d_in[0];
  const float* w1  = (const float*)d_in[1];
  const float* b1  = (const float*)d_in[2];
  const float* w2  = (const float*)d_in[3];
  const float* b2  = (const float*)d_in[4];
  const float* w3  = (const float*)d_in[5];
  const float* b3  = (const float*)d_in[6];
  const float* wl  = (const float*)d_in[7];
  const float* bl  = (const float*)d_in[8];
  // d_in[9..14] = wc1,bc1,wc2,bc2,wc3,bc3: dead (gate sigmoid <= 1 -> mask always False)

  float* out = (float*)d_out;

  hipLaunchKernelGGL(fused_kernel, dim3(2*NBLK), dim3(256), 0, stream,
                     inp, w1, b1, w2, b2, w3, b3, wl, bl, out);
}

// Round 14
// 254.324 us; speedup vs baseline: 1.1684x; 1.0118x over previous
//
#include <hip/hip_runtime.h>
#include <math.h>

// Problem constants
#define CC 3
#define HH 1280
#define WW 720
#define BSZ 20
#define NHB 64
#define NWB 36
#define NBLK (NHB*NWB)          // 2304
#define OUT_IMG (3*5120*2880)   // 44236800

#define SLAB_PITCH 84           // 80 cols + pad; 84 % 32 = 20 -> row-bank offsets distinct
#define SLAB_ROWS  60           // 3 c * 20 out-rows per slab (5 conv rows x 4 r1 x 3 c)

// Union'd LDS: light and gate are block-uniform branches of one kernel.
// r13 change: LDS DIET ONLY. Compute structure identical to r9/r12 (best
// measured, 107us kernel). Light drops w_s/b_s (weights read from global,
// L2-hot); gate aliases red[] over the stage-A-only ins/w1t/b1s region and
// reads w3 from global. Union max 31.9 -> ~25.9 KB => 6 blocks/CU (was 5),
// +20% resident waves for a latency/TLP-bound kernel.
union __align__(16) SMem {
  struct {
    float in_s[3][22][24];             // zero-padded input block (6336 B)
    float slab[SLAB_ROWS][SLAB_PITCH]; // pixel-shuffled output slab (20160 B)
  } L;                                  // ~25.9 KB
  struct {
    union {
      struct {
        float ins[3][26][28];          // clamped input patch (stage A only)
        float w1t[27][16];             // transposed conv1 weights (stage A only)
        float b1s[16];                 // (stage A only)
      } a;                              // 10528 B
      float red[256];                  // stage B/C reduction buffer (aliases ins)
    } u;
    float w2t[16][9][8];               // transposed conv2 weights [ic][k][oc2]
    float b2s[8];
    float x1s[16][12][14];             // post-pool conv1 patch, cols padded to 14
    float b3s;
  } G;                                  // ~25.3 KB
};

__device__ __forceinline__ float fast_tanh(float x) {
  const float ax = fabsf(x);
  const float e = __expf(-2.0f * ax);
  const float t = (1.0f - e) / (1.0f + e);
  return x < 0.0f ? -t : t;
}

// ---------------------------------------------------------------------------
// Light expert: per 20x20 block, zero-pad conv3x3 (3->48) + pixel_shuffle(4)
// + clamp[0,0.6]+0.4. mask always False -> complex expert dead.
// Thread = one (oc,hl) with acc[20] (the PROVEN 48-VGPR conv structure).
// Weights: per-thread from GLOBAL (27 dwords + bias; 5 threads share each
// address, wl is 5KB L2-hot) - removes w_s from LDS.
// Wave-private slab (r9-validated): every slab row is written by exactly one
// wave; each wave drains its own 16 rows right after writing (in-wave DS
// ordering via lgkmcnt, no __syncthreads). 2 barriers total.
// r8 lesson: direct global scatter stores WORSE (VMEM backpressure).
// r11 lesson: 2-oc/thread (120-thread conv) WORSE (TLP collapse).
// ---------------------------------------------------------------------------
__device__ __forceinline__ void light_body(
    SMem& sm, int l,
    const float* __restrict__ inp,
    const float* __restrict__ wl,
    const float* __restrict__ bl,
    float* __restrict__ out) {
  const int bi = l / NWB, bj = l % NWB;
  const int tid = threadIdx.x;

  for (int i = tid; i < 3*22*24; i += 256) ((float*)sm.L.in_s)[i] = 0.0f;
  __syncthreads();
  // stage 20x20x3 block; global float4 loads (WW=720 and 20*bj are mult of 4)
  for (int i = tid; i < 300; i += 256) {
    int x4 = i % 5; int r = (i / 5) % 20; int c = i / 100;
    const float4 v = *(const float4*)&inp[(c*HH + bi*BSZ + r)*WW + bj*BSZ + 4*x4];
    float* dst = &sm.L.in_s[c][r+1][1 + 4*x4];
    dst[0] = v.x; dst[1] = v.y; dst[2] = v.z; dst[3] = v.w;
  }
  __syncthreads();

  if (tid < 240) {
    const int oc = tid % 48;
    const int hl = tid / 48;            // 0..4: conv row within slab
    const int c  = oc >> 4;             // pixel-shuffle: c  = oc>>4
    const int r1 = (oc >> 2) & 3;       //                r1 = (oc>>2)&3
    const int r2 = oc & 3;              //                r2 = oc&3

    // weights from global (slab-invariant, L2-hot, 5 threads/address)
    float wr[27];
    #pragma unroll
    for (int j = 0; j < 27; ++j) wr[j] = wl[oc*27 + j];
    const float bias = bl[oc];

    // wave-private drain geometry: wave wv owns quads j = 16*wv + rloc
    const int wv    = tid >> 6;                  // 0..3
    const int lane  = tid & 63;
    const int nlane = (wv == 3) ? 48 : 64;       // wave 3 has lanes 192..239
    const int nf4   = (wv == 3) ? 240 : 320;     // own_rows * 20 float4s
    const int row0 = bi * 80, col0 = bj * 80;

    #pragma unroll 1
    for (int slab = 0; slab < 4; ++slab) {
      const int h = slab*5 + hl;
      float acc[20];
      #pragma unroll
      for (int w = 0; w < 20; ++w) acc[w] = bias;

      #pragma unroll
      for (int ic = 0; ic < 3; ++ic)
        #pragma unroll
        for (int ky = 0; ky < 3; ++ky) {
          const float* row = &sm.L.in_s[ic][h + ky][0];
          float r[24];
          #pragma unroll
          for (int j = 0; j < 6; ++j) {
            float4 v = ((const float4*)row)[j];   // ds_read_b128, 2 addrs/wave
            r[j*4+0] = v.x; r[j*4+1] = v.y; r[j*4+2] = v.z; r[j*4+3] = v.w;
          }
          const float w0 = wr[ic*9 + ky*3 + 0];
          const float w1 = wr[ic*9 + ky*3 + 1];
          const float w2 = wr[ic*9 + ky*3 + 2];
          #pragma unroll
          for (int w = 0; w < 20; ++w)
            acc[w] += r[w]*w0 + r[w+1]*w1 + r[w+2]*w2;
        }

      // pixel_shuffle scatter -> wave-private slab row
      float* dst = &sm.L.slab[c*20 + hl*4 + r1][r2];
      #pragma unroll
      for (int w = 0; w < 20; ++w)
        dst[4*w] = fminf(fmaxf(acc[w], 0.0f), 0.6f) + 0.4f;

      // wave-local drain of this wave's own rows (no __syncthreads needed:
      // rows written only by this wave; lgkmcnt orders write->read in-wave)
      #pragma unroll 1
      for (int q = lane; q < nf4; q += nlane) {
        const int rloc = q / 20, cb = q % 20;
        const int j    = 16*wv + rloc;           // quad id -> (hl_j, c_j, r1_j)
        const int hl_j = j / 12;
        const int rem  = j - hl_j*12;
        const int c_j  = rem >> 2;
        const int r1_j = rem & 3;
        const float4 v = *(const float4*)&sm.L.slab[(c_j*20 + hl_j*4 + r1_j)][4*cb];
        const int gy = row0 + slab*20 + hl_j*4 + r1_j;
        *(float4*)&out[(c_j*5120 + gy)*2880 + col0 + 4*cb] = v;
      }
      // next slab's writes to the same rows are ordered after these reads
      // within the wave (program order); other waves never touch them.
    }
  }
}

// ---------------------------------------------------------------------------
// Fused gate CNN (r7 compute structure; red[] aliases the stage-A region,
// w3 read from global in stage B):
//   stage A: 4 oc per patch load (patch LDS reads /4, float2 reads, float4 w)
//   stage B: 4 oc2 per window (window LDS reads /4, float4 broadcast weights)
//   stage C: reduce 200 products + sigmoid
// ---------------------------------------------------------------------------
__device__ __forceinline__ void gate_body(
    SMem& sm, int l,
    const float* __restrict__ inp,
    const float* __restrict__ w1,
    const float* __restrict__ b1,
    const float* __restrict__ w2,
    const float* __restrict__ b2,
    const float* __restrict__ w3,
    const float* __restrict__ b3,
    float* __restrict__ cv) {
  const int tid = threadIdx.x;
  const int oy = l / NWB, ox = l % NWB;

  // transposed conv1 weights: w1t[k][oc] = w1[oc*27 + k]
  for (int i = tid; i < 27*16; i += 256) {
    int k = i >> 4, oc = i & 15;
    sm.G.u.a.w1t[k][oc] = w1[oc*27 + k];
  }
  // transposed conv2 weights: w2t[ic][k][oc2] = w2[(oc2*16+ic)*9 + k]
  for (int i = tid; i < 16*9*8; i += 256) {
    int ic = i / 72; int rem = i - ic*72; int k = rem >> 3; int oc2 = rem & 7;
    ((float*)sm.G.w2t)[i] = w2[(oc2*16 + ic)*9 + k];
  }
  if (tid < 16) sm.G.u.a.b1s[tid] = b1[tid];
  if (tid < 8)  sm.G.b2s[tid] = b2[tid];
  if (tid == 0) sm.G.b3s = b3[0];

  // input patch rows [20*oy-3, 20*oy+23), cols [20*ox-3, 20*ox+23), clamped
  for (int i = tid; i < 3*26*28; i += 256) {
    int b = i % 28; int a = (i / 28) % 26; int ic = i / (26*28);
    int gy = 20*oy - 3 + a; gy = gy < 0 ? 0 : (gy > HH-1 ? HH-1 : gy);
    int gx = 20*ox - 3 + b; gx = gx < 0 ? 0 : (gx > WW-1 ? WW-1 : gx);
    sm.G.u.a.ins[ic][a][b] = inp[(ic*HH + gy)*WW + gx];
  }
  __syncthreads();

  // ---- stage A: 4 oc per thread-iteration, patch loaded once per 4 oc
  for (int idx = tid; idx < 4*144; idx += 256) {
    const int ocq = idx / 144;                 // 0..3 -> oc = 4*ocq + q
    const int pos = idx - ocq*144;
    const int ly = pos / 12, lx = pos - ly*12;
    int y1 = 10*oy - 1 + ly; y1 = y1 < 0 ? 0 : (y1 > 639 ? 639 : y1);
    int x1 = 10*ox - 1 + lx; x1 = x1 < 0 ? 0 : (x1 > 359 ? 359 : x1);
    const int ry = 2*y1 + 2 - 20*oy;           // even, in [0,22]
    const int rx = 2*x1 + 2 - 20*ox;           // even, in [0,24]

    float patch[3][4][4];
    #pragma unroll
    for (int ic = 0; ic < 3; ++ic)
      #pragma unroll
      for (int d = 0; d < 4; ++d) {
        const float2 pa = *(const float2*)&sm.G.u.a.ins[ic][ry + d][rx];
        const float2 pb = *(const float2*)&sm.G.u.a.ins[ic][ry + d][rx + 2];
        patch[ic][d][0] = pa.x; patch[ic][d][1] = pa.y;
        patch[ic][d][2] = pb.x; patch[ic][d][3] = pb.y;
      }

    const float4 b4 = *(const float4*)&sm.G.u.a.b1s[4*ocq];
    float a00[4], a01[4], a10[4], a11[4];
    a00[0]=b4.x; a00[1]=b4.y; a00[2]=b4.z; a00[3]=b4.w;
    a01[0]=b4.x; a01[1]=b4.y; a01[2]=b4.z; a01[3]=b4.w;
    a10[0]=b4.x; a10[1]=b4.y; a10[2]=b4.z; a10[3]=b4.w;
    a11[0]=b4.x; a11[1]=b4.y; a11[2]=b4.z; a11[3]=b4.w;

    #pragma unroll
    for (int ic = 0; ic < 3; ++ic)
      #pragma unroll
      for (int ky = 0; ky < 3; ++ky)
        #pragma unroll
        for (int kx = 0; kx < 3; ++kx) {
          const int k = (ic*3 + ky)*3 + kx;
          const float4 wv = *(const float4*)&sm.G.u.a.w1t[k][4*ocq];
          const float p00 = patch[ic][ky  ][kx  ];
          const float p01 = patch[ic][ky  ][kx+1];
          const float p10 = patch[ic][ky+1][kx  ];
          const float p11 = patch[ic][ky+1][kx+1];
          a00[0] += p00*wv.x; a00[1] += p00*wv.y; a00[2] += p00*wv.z; a00[3] += p00*wv.w;
          a01[0] += p01*wv.x; a01[1] += p01*wv.y; a01[2] += p01*wv.z; a01[3] += p01*wv.w;
          a10[0] += p10*wv.x; a10[1] += p10*wv.y; a10[2] += p10*wv.z; a10[3] += p10*wv.w;
          a11[0] += p11*wv.x; a11[1] += p11*wv.y; a11[2] += p11*wv.z; a11[3] += p11*wv.w;
        }

    #pragma unroll
    for (int q = 0; q < 4; ++q) {
      const float m = fmaxf(fmaxf(a00[q], a01[q]), fmaxf(a10[q], a11[q]));
      // tanh monotonic: maxpool(tanh(.)) == tanh(maxpool(.))
      sm.G.x1s[4*ocq + q][ly][lx] = fast_tanh(m);
    }
  }
  __syncthreads();
  // ins/w1t/b1s are DEAD from here; red[] aliases that region (union).

  // ---- stage B: 4 oc2 per thread; x1s window read once per oc2-quad.
  sm.G.u.red[tid] = 0.0f;
  __syncthreads();
  if (tid < 50) {
    const int q   = tid / 25;
    const int win = tid - q*25;
    const int j = win / 5, i5 = win - j*5;

    const float4 b4 = *(const float4*)&sm.G.b2s[4*q];
    float a00[4], a01[4], a10[4], a11[4];
    a00[0]=b4.x; a00[1]=b4.y; a00[2]=b4.z; a00[3]=b4.w;
    a01[0]=b4.x; a01[1]=b4.y; a01[2]=b4.z; a01[3]=b4.w;
    a10[0]=b4.x; a10[1]=b4.y; a10[2]=b4.z; a10[3]=b4.w;
    a11[0]=b4.x; a11[1]=b4.y; a11[2]=b4.z; a11[3]=b4.w;

    for (int ic = 0; ic < 16; ++ic) {
      float p[4][4];
      #pragma unroll
      for (int d = 0; d < 4; ++d) {
        const float2 pa = *(const float2*)&sm.G.x1s[ic][2*j + d][2*i5];
        const float2 pb = *(const float2*)&sm.G.x1s[ic][2*j + d][2*i5 + 2];
        p[d][0] = pa.x; p[d][1] = pa.y; p[d][2] = pb.x; p[d][3] = pb.y;
      }
      #pragma unroll
      for (int ky = 0; ky < 3; ++ky)
        #pragma unroll
        for (int kx = 0; kx < 3; ++kx) {
          const float4 wv = *(const float4*)&sm.G.w2t[ic][ky*3 + kx][4*q];
          const float p00 = p[ky  ][kx  ];
          const float p01 = p[ky  ][kx+1];
          const float p10 = p[ky+1][kx  ];
          const float p11 = p[ky+1][kx+1];
          a00[0] += p00*wv.x; a00[1] += p00*wv.y; a00[2] += p00*wv.z; a00[3] += p00*wv.w;
          a01[0] += p01*wv.x; a01[1] += p01*wv.y; a01[2] += p01*wv.z; a01[3] += p01*wv.w;
          a10[0] += p10*wv.x; a10[1] += p10*wv.y; a10[2] += p10*wv.z; a10[3] += p10*wv.w;
          a11[0] += p11*wv.x; a11[1] += p11*wv.y; a11[2] += p11*wv.z; a11[3] += p11*wv.w;
        }
    }
    #pragma unroll
    for (int qq = 0; qq < 4; ++qq) {
      const float x2 = fmaxf(fmaxf(a00[qq], a01[qq]), fmaxf(a10[qq], a11[qq]));
      const int o2 = 4*q + qq;
      sm.G.u.red[o2*25 + win] = x2 * w3[o2*25 + win];   // w3 from global (L2-hot)
    }
  }
  __syncthreads();

  // ---- stage C
  if (tid < 64) {
    float s = sm.G.u.red[tid] + sm.G.u.red[tid+64] + sm.G.u.red[tid+128] + sm.G.u.red[tid+192];
    #pragma unroll
    for (int off = 32; off > 0; off >>= 1) s += __shfl_down(s, off);
    if (tid == 0)
      cv[l] = 1.0f / (1.0f + expf(-(s + sm.G.b3s)));
  }
}

// ---------------------------------------------------------------------------
// One launch, interleaved light/gate blocks (block-uniform branch).
// ---------------------------------------------------------------------------
__global__ __launch_bounds__(256) void fused_kernel(
    const float* __restrict__ inp,
    const float* __restrict__ w1,
    const float* __restrict__ b1,
    const float* __restrict__ w2,
    const float* __restrict__ b2,
    const float* __restrict__ w3,
    const float* __restrict__ b3,
    const float* __restrict__ wl,
    const float* __restrict__ bl,
    float* __restrict__ out) {
  __shared__ SMem sm;
  const int bid = blockIdx.x;
  if (bid & 1)
    gate_body(sm, bid >> 1, inp, w1, b1, w2, b2, w3, b3, out + OUT_IMG);
  else
    light_body(sm, bid >> 1, inp, wl, bl, out);
}

// ---------------------------------------------------------------------------
extern "C" void kernel_launch(void* const* d_in, const int* in_sizes, int n_in,
                              void* d_out, int out_size, void* d_ws, size_t ws_size,
                              hipStream_t stream) {
  const float* inp = (const float*)d_in[0];
  const float* w1  = (const float*)d_in[1];
  const float* b1  = (const float*)d_in[2];
  const float* w2  = (const float*)d_in[3];
  const float* b2  = (const float*)d_in[4];
  const float* w3  = (const float*)d_in[5];
  const float* b3  = (const float*)d_in[6];
  const float* wl  = (const float*)d_in[7];
  const float* bl  = (const float*)d_in[8];
  // d_in[9..14] = wc1,bc1,wc2,bc2,wc3,bc3: dead (gate sigmoid <= 1 -> mask always False)

  float* out = (float*)d_out;

  hipLaunchKernelGGL(fused_kernel, dim3(2*NBLK), dim3(256), 0, stream,
                     inp, w1, b1, w2, b2, w3, b3, wl, bl, out);
}